// Round 1
// baseline (140.957 us; speedup 1.0000x reference)
//
#include <hip/hip_runtime.h>

#define DIM_IN   8192
#define DIM_OUT  8192
#define FAN      16
#define BATCH    1024
#define NNZ      (DIM_IN * FAN)
#define ROWS     4            // batch rows per block (x-rows staged in LDS)
#define BLOCK    1024
#define LDS_BYTES (DIM_IN * ROWS * 4)   // 128 KiB

// ---------------- CSR-by-output build (runs every call; ws is poisoned) ----

__global__ void zero_counts_kernel(int* __restrict__ counts) {
    counts[blockIdx.x * 256 + threadIdx.x] = 0;
}

__global__ void build_idx_kernel(const int* __restrict__ pre,
                                 const int* __restrict__ post,
                                 int* __restrict__ counts,
                                 int* __restrict__ idx) {
    int e = blockIdx.x * 256 + threadIdx.x;
    if (e < NNZ) {
        int j = post[e];
        int slot = atomicAdd(&counts[j], 1);   // each j gets exactly FAN edges
        idx[j * FAN + slot] = pre[e];
    }
}

// ---------------- main gather kernel ---------------------------------------
// Block = 4 batch rows staged in LDS interleaved: lds[i*4 + r] = x[b0+r][i].
// Each thread owns outputs j = tid + o*BLOCK; per output: 16 ds_read_b128
// gathers (4 rows at once), accumulate into float4, scale by 100, store.

__global__ __launch_bounds__(BLOCK, 4)
void gather_kernel(const float* __restrict__ x,
                   const int*   __restrict__ idx,
                   float*       __restrict__ y) {
    extern __shared__ float lds[];           // [DIM_IN][ROWS] interleaved
    const int t  = threadIdx.x;
    const int b0 = blockIdx.x * ROWS;

    // Stage 4 rows of x. Lane i loads x[b0+r][i] for r=0..3, writes one b128.
    // Global: 4 coalesced dword streams. LDS: consecutive lanes write
    // consecutive 16B -> conflict-free ds_write_b128.
    const float* xr0 = x + (size_t)(b0 + 0) * DIM_IN;
    const float* xr1 = x + (size_t)(b0 + 1) * DIM_IN;
    const float* xr2 = x + (size_t)(b0 + 2) * DIM_IN;
    const float* xr3 = x + (size_t)(b0 + 3) * DIM_IN;
#pragma unroll
    for (int c = 0; c < DIM_IN / BLOCK; ++c) {
        int i = t + c * BLOCK;
        float4 v;
        v.x = xr0[i];
        v.y = xr1[i];
        v.z = xr2[i];
        v.w = xr3[i];
        *reinterpret_cast<float4*>(&lds[i * 4]) = v;
    }
    __syncthreads();

    float*       y0 = y + (size_t)(b0 + 0) * DIM_OUT;
    float*       y1 = y + (size_t)(b0 + 1) * DIM_OUT;
    float*       y2 = y + (size_t)(b0 + 2) * DIM_OUT;
    float*       y3 = y + (size_t)(b0 + 3) * DIM_OUT;

#pragma unroll
    for (int o = 0; o < DIM_OUT / BLOCK; ++o) {
        const int j = t + o * BLOCK;
        // 64B of indices per output, consecutive threads -> consecutive 64B.
        const int4* ip = reinterpret_cast<const int4*>(idx + (size_t)j * FAN);
        int4 i0 = ip[0];
        int4 i1 = ip[1];
        int4 i2 = ip[2];
        int4 i3 = ip[3];

        float4 acc = make_float4(0.f, 0.f, 0.f, 0.f);
        auto accum = [&](int i) {
            float4 v = *reinterpret_cast<const float4*>(&lds[i * 4]);
            acc.x += v.x; acc.y += v.y; acc.z += v.z; acc.w += v.w;
        };
        accum(i0.x); accum(i0.y); accum(i0.z); accum(i0.w);
        accum(i1.x); accum(i1.y); accum(i1.z); accum(i1.w);
        accum(i2.x); accum(i2.y); accum(i2.z); accum(i2.w);
        accum(i3.x); accum(i3.y); accum(i3.z); accum(i3.w);

        y0[j] = 100.0f * acc.x;
        y1[j] = 100.0f * acc.y;
        y2[j] = 100.0f * acc.z;
        y3[j] = 100.0f * acc.w;
    }
}

// ---------------- launch ---------------------------------------------------

extern "C" void kernel_launch(void* const* d_in, const int* in_sizes, int n_in,
                              void* d_out, int out_size, void* d_ws, size_t ws_size,
                              hipStream_t stream) {
    const float* x    = (const float*)d_in[0];
    const int*   pre  = (const int*)d_in[1];
    const int*   post = (const int*)d_in[2];
    float*       y    = (float*)d_out;

    int* counts = (int*)d_ws;                 // DIM_OUT ints
    int* idx    = counts + DIM_OUT;           // NNZ ints

    // Allow 128 KiB dynamic LDS (idempotent; not a stream op).
    hipFuncSetAttribute((const void*)gather_kernel,
                        hipFuncAttributeMaxDynamicSharedMemorySize, LDS_BYTES);

    zero_counts_kernel<<<DIM_OUT / 256, 256, 0, stream>>>(counts);
    build_idx_kernel<<<(NNZ + 255) / 256, 256, 0, stream>>>(pre, post, counts, idx);
    gather_kernel<<<BATCH / ROWS, BLOCK, LDS_BYTES, stream>>>(x, idx, y);
}